// Round 10
// baseline (312.031 us; speedup 1.0000x reference)
//
#include <hip/hip_runtime.h>

#define T_SEQ 2048
#define CDIM  1024
#define NH    16
#define DH    64
#define BDIM  2

typedef __bf16 bf16x8 __attribute__((ext_vector_type(8)));
typedef __bf16 bf16x4v __attribute__((ext_vector_type(4)));
typedef float  f32x4  __attribute__((ext_vector_type(4)));

static __device__ __forceinline__ f32x4 mfma16(bf16x8 a, bf16x8 b, f32x4 c) {
    return __builtin_amdgcn_mfma_f32_16x16x32_bf16(a, b, c, 0, 0, 0);
}

#define GLD_TO_LDS16(g, l) __builtin_amdgcn_global_load_lds( \
    (const __attribute__((address_space(1))) void*)(g),      \
    (__attribute__((address_space(3))) void*)(l), 16, 0, 0)

// ---------------- fused prep: x fp32->bf16 (blocks 0..4095) +
//                  W [K][N] fp32 -> Wt [N][K] bf16, 4 weights (blocks 4096..8191)
__global__ void k_prep(const float* __restrict__ x, __bf16* __restrict__ xb,
                       const float* __restrict__ Wq, const float* __restrict__ Wk,
                       const float* __restrict__ Wv, const float* __restrict__ Wp,
                       __bf16* __restrict__ Wt) {
    const int blk = blockIdx.x;
    if (blk < 4096) {                 // ---- convert body ----
        int i = blk * blockDim.x + threadIdx.x;   // n4 = 4096*256 exactly
        const float4 v = reinterpret_cast<const float4*>(x)[i];
        bf16x4v o = { (__bf16)v.x, (__bf16)v.y, (__bf16)v.z, (__bf16)v.w };
        reinterpret_cast<bf16x4v*>(xb)[i] = o;
    } else {                          // ---- transpose body ----
        __shared__ float tile[32][33];
        const int r = blk - 4096;
        const int bx = r & 31, by = (r >> 5) & 31, bz = r >> 10;
        const float* W = bz == 0 ? Wq : bz == 1 ? Wk : bz == 2 ? Wv : Wp;
        int tx = threadIdx.x & 31, ty = threadIdx.x >> 5;
        int n0 = bx * 32, k0 = by * 32;
#pragma unroll
        for (int j = 0; j < 4; ++j)
            tile[ty + j * 8][tx] = W[(size_t)(k0 + ty + j * 8) * CDIM + n0 + tx];
        __syncthreads();
        __bf16* dst = Wt + (size_t)bz * CDIM * CDIM;
#pragma unroll
        for (int j = 0; j < 4; ++j)
            dst[(size_t)(n0 + ty + j * 8) * CDIM + k0 + tx] = (__bf16)tile[tx][ty + j * 8];
    }
}

// ---------------- GEMM: out = A[M][1024] @ Wt^T + bias ----------------
// MODE 0: QKV fused (N=3072): writes Qb (scaled 1/8), Kb ([B,T,C] bf16), Vt ([B,H,Dh,T] bf16)
// MODE 1: out-proj (N=1024): writes fp32 d_out
#define BM 128
#define BN 128
#define BKK 64

template <int MODE>
__global__ __launch_bounds__(256) void k_gemm(
    const __bf16* __restrict__ A, const __bf16* __restrict__ Bt,
    const float* __restrict__ b0, const float* __restrict__ b1, const float* __restrict__ b2,
    __bf16* __restrict__ outQ, __bf16* __restrict__ outK, __bf16* __restrict__ outVt,
    float* __restrict__ outF)
{
    __shared__ __bf16 ldsA[BM * BKK];
    __shared__ __bf16 ldsB[BN * BKK];
    const int tid = threadIdx.x;
    const int lane = tid & 63, w = tid >> 6;
    const int g = lane >> 4, l15 = lane & 15;

    // XCD-aware bijective swizzle (T1): nwg is a multiple of 8 for both modes.
    const int nwg = gridDim.x * gridDim.y;
    const int flat = blockIdx.y * gridDim.x + blockIdx.x;
    const int cpx = nwg >> 3;
    const int f2 = (flat & 7) * cpx + (flat >> 3);
    const int bx = f2 % gridDim.x, by = f2 / gridDim.x;

    const int m0 = by * BM, n0 = bx * BN;
    const int wr = w >> 1, wc = w & 1;

    f32x4 acc[4][4];
#pragma unroll
    for (int ma = 0; ma < 4; ++ma)
#pragma unroll
        for (int nb = 0; nb < 4; ++nb)
            acc[ma][nb] = (f32x4){0.f, 0.f, 0.f, 0.f};

    for (int kt = 0; kt < CDIM / BKK; ++kt) {
        const int k0 = kt * BKK;
        // stage A then B: LDS chunk L holds global chunk (r = L>>3, c = (L&7) ^ (r&7))
        // (swizzle on the GLOBAL source side; LDS stays linear -> 2-way-free ds_read)
#pragma unroll
        for (int j = 0; j < 4; ++j) {
            int L = j * 256 + tid;
            int r = L >> 3, cd = (L & 7) ^ (r & 7);
            GLD_TO_LDS16(A + (size_t)(m0 + r) * CDIM + k0 + cd * 8,
                         ldsA + (size_t)(j * 256 + w * 64) * 8);
        }
#pragma unroll
        for (int j = 0; j < 4; ++j) {
            int L = j * 256 + tid;
            int r = L >> 3, cd = (L & 7) ^ (r & 7);
            GLD_TO_LDS16(Bt + (size_t)(n0 + r) * CDIM + k0 + cd * 8,
                         ldsB + (size_t)(j * 256 + w * 64) * 8);
        }
        __syncthreads();
#pragma unroll
        for (int ks = 0; ks < 2; ++ks) {
            bf16x8 af[4], bfr[4];
#pragma unroll
            for (int ma = 0; ma < 4; ++ma) {
                int r = wr * 64 + ma * 16 + l15;
                int c = ks * 4 + g;
                af[ma] = *reinterpret_cast<const bf16x8*>(ldsA + (r * 8 + (c ^ (r & 7))) * 8);
            }
#pragma unroll
            for (int nb = 0; nb < 4; ++nb) {
                int r = wc * 64 + nb * 16 + l15;
                int c = ks * 4 + g;
                bfr[nb] = *reinterpret_cast<const bf16x8*>(ldsB + (r * 8 + (c ^ (r & 7))) * 8);
            }
#pragma unroll
            for (int ma = 0; ma < 4; ++ma)
#pragma unroll
                for (int nb = 0; nb < 4; ++nb)
                    acc[ma][nb] = mfma16(af[ma], bfr[nb], acc[ma][nb]);
        }
        __syncthreads();
    }

    // epilogue: D frag mapping col = lane&15, row = (lane>>4)*4 + i  (m89-verified)
#pragma unroll
    for (int ma = 0; ma < 4; ++ma)
#pragma unroll
        for (int nb = 0; nb < 4; ++nb) {
            const int n = n0 + wc * 64 + nb * 16 + l15;
#pragma unroll
            for (int i = 0; i < 4; ++i) {
                const int m = m0 + wr * 64 + ma * 16 + g * 4 + i;
                float v = acc[ma][nb][i];
                if (MODE == 0) {
                    const int sel = n >> 10, nc = n & 1023;
                    v += (sel == 0 ? b0 : sel == 1 ? b1 : b2)[nc];
                    if (sel == 0) {
                        outQ[(size_t)m * CDIM + nc] = (__bf16)(v * 0.125f);
                    } else if (sel == 1) {
                        outK[(size_t)m * CDIM + nc] = (__bf16)v;
                    } else {
                        const int bb = m >> 11, t = m & (T_SEQ - 1);
                        const int h = nc >> 6, dh = nc & 63;
                        outVt[((size_t)((bb * NH + h) * DH + dh)) * T_SEQ + t] = (__bf16)v;
                    }
                } else {
                    outF[(size_t)m * CDIM + n] = v + b0[n];
                }
            }
        }
}

// ---------------- causal flash attention ----------------
// grid 1024 blocks (1D), 256 thr, one 64-row q-tile per block.
// In-kernel bijective remap (flat%8 ~ XCD): xcd f&7 owns heads {f&7, +8, +16, +24}
// -> 4 heads x 512KB KV = 2MB per XCD-L2 (fits 4MB, was 16MB thrash = 121MB fetch).
// qt descends with dispatch order -> longest blocks first, short blocks fill tail.
// Wave w owns 16 q-rows; swapped QK^T (mfma(K,Q)) -> lane-local softmax;
// T5 setprio (waves independent); T13 defer-max.
__global__ __launch_bounds__(256) void k_attn(const __bf16* __restrict__ Q,
                                              const __bf16* __restrict__ K,
                                              const __bf16* __restrict__ Vt,
                                              __bf16* __restrict__ Y)
{
    __shared__ __bf16 ldsP[4][16 * 72];   // per-wave, stride 72 shorts
    const int tid = threadIdx.x;
    const int lane = tid & 63, w = tid >> 6;
    const int g = lane >> 4, l15 = lane & 15;

    const int f = blockIdx.x;             // 0..1023
    const int i = f >> 3;                 // 0..127
    const int bh = (f & 7) | ((i & 3) << 3);          // head group per XCD
    const int qt = (T_SEQ / 64 - 1) - (i >> 2);       // 31..0, longest first
    const int b = bh >> 4, h = bh & 15;
    const int q0 = qt * 64 + w * 16;

    const __bf16* Kb_ = K + (size_t)(b * T_SEQ) * CDIM + h * DH;
    const __bf16* Vb_ = Vt + (size_t)(b * NH + h) * DH * T_SEQ;
    __bf16* Pw = &ldsP[w][0];

    const __bf16* Qrow = Q + (size_t)(b * T_SEQ + q0 + l15) * CDIM + h * DH;
    const bf16x8 qf0 = *reinterpret_cast<const bf16x8*>(Qrow + g * 8);
    const bf16x8 qf1 = *reinterpret_cast<const bf16x8*>(Qrow + 32 + g * 8);

    f32x4 o[4];
#pragma unroll
    for (int nf = 0; nf < 4; ++nf) o[nf] = (f32x4){0.f, 0.f, 0.f, 0.f};
    float m_run = -1e30f, l_run = 0.f;

    for (int t = 0; t <= qt; ++t) {
        const int kv0 = t * 64;
        // S^T tile: lane holds col q = q0+l15, rows k = kv0 + kb*16 + g*4 + i
        f32x4 s[4];
        __builtin_amdgcn_s_setprio(1);
#pragma unroll
        for (int kb = 0; kb < 4; ++kb) {
            const __bf16* Krow = Kb_ + (size_t)(kv0 + kb * 16 + l15) * CDIM;
            const bf16x8 kf0 = *reinterpret_cast<const bf16x8*>(Krow + g * 8);
            const bf16x8 kf1 = *reinterpret_cast<const bf16x8*>(Krow + 32 + g * 8);
            f32x4 z = (f32x4){0.f, 0.f, 0.f, 0.f};
            z = mfma16(kf0, qf0, z);
            z = mfma16(kf1, qf1, z);
            s[kb] = z;
        }
        __builtin_amdgcn_s_setprio(0);
        if (t == qt) {   // diagonal tile: causal mask
#pragma unroll
            for (int kb = 0; kb < 4; ++kb)
#pragma unroll
                for (int ii = 0; ii < 4; ++ii)
                    if (kv0 + kb * 16 + g * 4 + ii > q0 + l15) s[kb][ii] = -1e30f;
        }
        float tm = -1e30f;
#pragma unroll
        for (int kb = 0; kb < 4; ++kb)
#pragma unroll
            for (int ii = 0; ii < 4; ++ii) tm = fmaxf(tm, s[kb][ii]);
        tm = fmaxf(tm, __shfl_xor(tm, 16));
        tm = fmaxf(tm, __shfl_xor(tm, 32));
        // T13 defer-max: only rescale when some row's max grew by > 8.
        if (!__all(tm - m_run <= 8.f)) {
            const float mnew = fmaxf(m_run, tm);
            const float alpha = __expf(m_run - mnew);
            l_run *= alpha;
#pragma unroll
            for (int ii = 0; ii < 4; ++ii) {
                const float ai = __shfl(alpha, g * 4 + ii);
#pragma unroll
                for (int nf = 0; nf < 4; ++nf) o[nf][ii] *= ai;
            }
            m_run = mnew;
        }
        float ts = 0.f;
#pragma unroll
        for (int kb = 0; kb < 4; ++kb)
#pragma unroll
            for (int ii = 0; ii < 4; ++ii) {
                const float p = __expf(s[kb][ii] - m_run);
                s[kb][ii] = p;
                ts += p;
            }
        ts += __shfl_xor(ts, 16);
        ts += __shfl_xor(ts, 32);
        l_run += ts;
        // P -> LDS [q=l15][k], 8B packed writes
#pragma unroll
        for (int kb = 0; kb < 4; ++kb) {
            bf16x4v pk = { (__bf16)s[kb][0], (__bf16)s[kb][1],
                           (__bf16)s[kb][2], (__bf16)s[kb][3] };
            *reinterpret_cast<bf16x4v*>(Pw + l15 * 72 + kb * 16 + g * 4) = pk;
        }
        // PV: A = P[q][k] from LDS, B = V[k][d] from Vt rows (contiguous k)
        __builtin_amdgcn_s_setprio(1);
#pragma unroll
        for (int ks = 0; ks < 2; ++ks) {
            const bf16x8 pf = *reinterpret_cast<const bf16x8*>(Pw + l15 * 72 + ks * 32 + g * 8);
#pragma unroll
            for (int nf = 0; nf < 4; ++nf) {
                const __bf16* Vrow = Vb_ + (size_t)(nf * 16 + l15) * T_SEQ + kv0 + ks * 32 + g * 8;
                const bf16x8 vf = *reinterpret_cast<const bf16x8*>(Vrow);
                o[nf] = mfma16(pf, vf, o[nf]);
            }
        }
        __builtin_amdgcn_s_setprio(0);
    }
    // epilogue: divide by l, write [B,T,C] bf16
#pragma unroll
    for (int ii = 0; ii < 4; ++ii) {
        const float li = __shfl(l_run, g * 4 + ii);
        const float inv = 1.f / li;
        __bf16* Yr = Y + (size_t)(b * T_SEQ + q0 + g * 4 + ii) * CDIM + h * DH;
#pragma unroll
        for (int nf = 0; nf < 4; ++nf)
            Yr[nf * 16 + l15] = (__bf16)(o[nf][ii] * inv);
    }
}

extern "C" void kernel_launch(void* const* d_in, const int* in_sizes, int n_in,
                              void* d_out, int out_size, void* d_ws, size_t ws_size,
                              hipStream_t stream) {
    const float* x  = (const float*)d_in[0];
    const float* Wq = (const float*)d_in[1];
    const float* bq = (const float*)d_in[2];
    const float* Wk = (const float*)d_in[3];
    const float* bk = (const float*)d_in[4];
    const float* Wv = (const float*)d_in[5];
    const float* bv = (const float*)d_in[6];
    const float* Wp = (const float*)d_in[7];
    const float* bp = (const float*)d_in[8];
    float* out = (float*)d_out;
    (void)in_sizes; (void)n_in; (void)out_size; (void)ws_size;

    char* ws = (char*)d_ws;
    const size_t MT = (size_t)BDIM * T_SEQ;                  // 4096 rows
    const size_t SZ = MT * CDIM * sizeof(__bf16);            // 8 MiB
    __bf16* Xb = (__bf16*)(ws);                              // [4096][1024]
    __bf16* Wt = (__bf16*)(ws + SZ);                         // [4096][1024] (q,k,v,p stacked)
    __bf16* Qb = (__bf16*)(ws + 2 * SZ);                     // [B,T,C] (pre-scaled 1/8)
    __bf16* Kb = (__bf16*)(ws + 3 * SZ);                     // [B,T,C]
    __bf16* Vt = (__bf16*)(ws + 4 * SZ);                     // [B,H,Dh,T]
    __bf16* Ya = Xb;                                         // alias: Xb dead after QKV gemm

    // fused convert+transpose: blocks [0,4096) convert x, [4096,8192) transpose W
    k_prep<<<dim3(8192), 256, 0, stream>>>(x, Xb, Wq, Wk, Wv, Wp, Wt);
    k_gemm<0><<<dim3(3 * CDIM / BN, MT / BM), 256, 0, stream>>>(
        Xb, Wt, bq, bk, bv, Qb, Kb, Vt, nullptr);
    k_attn<<<dim3(T_SEQ / 64 * BDIM * NH), 256, 0, stream>>>(Qb, Kb, Vt, Ya);
    k_gemm<1><<<dim3(CDIM / BN, MT / BM), 256, 0, stream>>>(
        Ya, Wt + (size_t)3 * CDIM * CDIM, bp, nullptr, nullptr,
        nullptr, nullptr, nullptr, out);
}

// Round 11
// 212.029 us; speedup vs baseline: 1.4716x; 1.4716x over previous
//
#include <hip/hip_runtime.h>

#define T_SEQ 2048
#define CDIM  1024
#define NH    16
#define DH    64
#define BDIM  2

typedef __bf16 bf16x8 __attribute__((ext_vector_type(8)));
typedef __bf16 bf16x4v __attribute__((ext_vector_type(4)));
typedef float  f32x4  __attribute__((ext_vector_type(4)));

static __device__ __forceinline__ f32x4 mfma16(bf16x8 a, bf16x8 b, f32x4 c) {
    return __builtin_amdgcn_mfma_f32_16x16x32_bf16(a, b, c, 0, 0, 0);
}

#define GLD_TO_LDS16(g, l) __builtin_amdgcn_global_load_lds( \
    (const __attribute__((address_space(1))) void*)(g),      \
    (__attribute__((address_space(3))) void*)(l), 16, 0, 0)

// ---------------- fused prep: x fp32->bf16 (blocks 0..4095) +
//                  W [K][N] fp32 -> Wt [N][K] bf16, 4 weights (blocks 4096..8191)
__global__ void k_prep(const float* __restrict__ x, __bf16* __restrict__ xb,
                       const float* __restrict__ Wq, const float* __restrict__ Wk,
                       const float* __restrict__ Wv, const float* __restrict__ Wp,
                       __bf16* __restrict__ Wt) {
    const int blk = blockIdx.x;
    if (blk < 4096) {                 // ---- convert body ----
        int i = blk * blockDim.x + threadIdx.x;   // n4 = 4096*256 exactly
        const float4 v = reinterpret_cast<const float4*>(x)[i];
        bf16x4v o = { (__bf16)v.x, (__bf16)v.y, (__bf16)v.z, (__bf16)v.w };
        reinterpret_cast<bf16x4v*>(xb)[i] = o;
    } else {                          // ---- transpose body ----
        __shared__ float tile[32][33];
        const int r = blk - 4096;
        const int bx = r & 31, by = (r >> 5) & 31, bz = r >> 10;
        const float* W = bz == 0 ? Wq : bz == 1 ? Wk : bz == 2 ? Wv : Wp;
        int tx = threadIdx.x & 31, ty = threadIdx.x >> 5;
        int n0 = bx * 32, k0 = by * 32;
#pragma unroll
        for (int j = 0; j < 4; ++j)
            tile[ty + j * 8][tx] = W[(size_t)(k0 + ty + j * 8) * CDIM + n0 + tx];
        __syncthreads();
        __bf16* dst = Wt + (size_t)bz * CDIM * CDIM;
#pragma unroll
        for (int j = 0; j < 4; ++j)
            dst[(size_t)(n0 + ty + j * 8) * CDIM + k0 + tx] = (__bf16)tile[tx][ty + j * 8];
    }
}

// ---------------- GEMM: out = A[M][1024] @ Wt^T + bias ----------------
// MODE 0: QKV fused (N=3072): writes Qb (scaled 1/8), Kb ([B,T,C] bf16), Vt ([B,H,Dh,T] bf16)
// MODE 1: out-proj (N=1024): writes fp32 d_out
#define BM 128
#define BN 128
#define BKK 64

template <int MODE>
__global__ __launch_bounds__(256) void k_gemm(
    const __bf16* __restrict__ A, const __bf16* __restrict__ Bt,
    const float* __restrict__ b0, const float* __restrict__ b1, const float* __restrict__ b2,
    __bf16* __restrict__ outQ, __bf16* __restrict__ outK, __bf16* __restrict__ outVt,
    float* __restrict__ outF)
{
    __shared__ __bf16 ldsA[BM * BKK];
    __shared__ __bf16 ldsB[BN * BKK];
    const int tid = threadIdx.x;
    const int lane = tid & 63, w = tid >> 6;
    const int g = lane >> 4, l15 = lane & 15;

    // XCD-aware bijective swizzle (T1): nwg is a multiple of 8 for both modes.
    const int nwg = gridDim.x * gridDim.y;
    const int flat = blockIdx.y * gridDim.x + blockIdx.x;
    const int cpx = nwg >> 3;
    const int f2 = (flat & 7) * cpx + (flat >> 3);
    const int bx = f2 % gridDim.x, by = f2 / gridDim.x;

    const int m0 = by * BM, n0 = bx * BN;
    const int wr = w >> 1, wc = w & 1;

    f32x4 acc[4][4];
#pragma unroll
    for (int ma = 0; ma < 4; ++ma)
#pragma unroll
        for (int nb = 0; nb < 4; ++nb)
            acc[ma][nb] = (f32x4){0.f, 0.f, 0.f, 0.f};

    for (int kt = 0; kt < CDIM / BKK; ++kt) {
        const int k0 = kt * BKK;
        // stage A then B: LDS chunk L holds global chunk (r = L>>3, c = (L&7) ^ (r&7))
#pragma unroll
        for (int j = 0; j < 4; ++j) {
            int L = j * 256 + tid;
            int r = L >> 3, cd = (L & 7) ^ (r & 7);
            GLD_TO_LDS16(A + (size_t)(m0 + r) * CDIM + k0 + cd * 8,
                         ldsA + (size_t)(j * 256 + w * 64) * 8);
        }
#pragma unroll
        for (int j = 0; j < 4; ++j) {
            int L = j * 256 + tid;
            int r = L >> 3, cd = (L & 7) ^ (r & 7);
            GLD_TO_LDS16(Bt + (size_t)(n0 + r) * CDIM + k0 + cd * 8,
                         ldsB + (size_t)(j * 256 + w * 64) * 8);
        }
        __syncthreads();
#pragma unroll
        for (int ks = 0; ks < 2; ++ks) {
            bf16x8 af[4], bfr[4];
#pragma unroll
            for (int ma = 0; ma < 4; ++ma) {
                int r = wr * 64 + ma * 16 + l15;
                int c = ks * 4 + g;
                af[ma] = *reinterpret_cast<const bf16x8*>(ldsA + (r * 8 + (c ^ (r & 7))) * 8);
            }
#pragma unroll
            for (int nb = 0; nb < 4; ++nb) {
                int r = wc * 64 + nb * 16 + l15;
                int c = ks * 4 + g;
                bfr[nb] = *reinterpret_cast<const bf16x8*>(ldsB + (r * 8 + (c ^ (r & 7))) * 8);
            }
#pragma unroll
            for (int ma = 0; ma < 4; ++ma)
#pragma unroll
                for (int nb = 0; nb < 4; ++nb)
                    acc[ma][nb] = mfma16(af[ma], bfr[nb], acc[ma][nb]);
        }
        __syncthreads();
    }

    // epilogue: D frag mapping col = lane&15, row = (lane>>4)*4 + i  (m89-verified)
#pragma unroll
    for (int ma = 0; ma < 4; ++ma)
#pragma unroll
        for (int nb = 0; nb < 4; ++nb) {
            const int n = n0 + wc * 64 + nb * 16 + l15;
#pragma unroll
            for (int i = 0; i < 4; ++i) {
                const int m = m0 + wr * 64 + ma * 16 + g * 4 + i;
                float v = acc[ma][nb][i];
                if (MODE == 0) {
                    const int sel = n >> 10, nc = n & 1023;
                    v += (sel == 0 ? b0 : sel == 1 ? b1 : b2)[nc];
                    if (sel == 0) {
                        outQ[(size_t)m * CDIM + nc] = (__bf16)(v * 0.125f);
                    } else if (sel == 1) {
                        outK[(size_t)m * CDIM + nc] = (__bf16)v;
                    } else {
                        const int bb = m >> 11, t = m & (T_SEQ - 1);
                        const int h = nc >> 6, dh = nc & 63;
                        outVt[((size_t)((bb * NH + h) * DH + dh)) * T_SEQ + t] = (__bf16)v;
                    }
                } else {
                    outF[(size_t)m * CDIM + n] = v + b0[n];
                }
            }
        }
}

// ---------------- causal flash attention (LDS-staged K/V, 2-phase dbuf) ------
// grid 512 blocks, 256 thr. Block f: xcd=f&7, i=f>>3; head bh=(f&7)|((i&3)<<3)
// (4 heads/XCD -> 2MB KV per XCD-L2); pair index pj=i>>2: q-tiles {pj, 31-pj}
// -> uniform 33 kv-tiles/block, 2 blocks/CU.
// Per kv-tile: K(8KB)+V(8KB) staged ONCE into LDS (was 4x redundant per-wave
// global reads), double-buffered; stage t+1 issued BEFORE computing t (T3
// 2-phase recipe) so L2 latency hides under compute. Global source chunk is
// XOR-preswizzled (j^=row&7, involution; LDS linear — rule #21) so ds_read_b128
// spreads 64 lanes over all 32 banks (optimal 8-cycle).
__global__ __launch_bounds__(256) void k_attn(const __bf16* __restrict__ Q,
                                              const __bf16* __restrict__ K,
                                              const __bf16* __restrict__ Vt,
                                              __bf16* __restrict__ Y)
{
    __shared__ __bf16 ldsK[2][64 * 64];
    __shared__ __bf16 ldsV[2][64 * 64];
    __shared__ __bf16 ldsP[4][16 * 72];
    const int tid = threadIdx.x;
    const int lane = tid & 63, w = tid >> 6;
    const int g = lane >> 4, l15 = lane & 15;

    const int f = blockIdx.x;             // 0..511
    const int i = f >> 3;                 // 0..63
    const int bh = (f & 7) | ((i & 3) << 3);
    const int pj = i >> 2;                // 0..15 pair index
    const int b = bh >> 4, h = bh & 15;

    const __bf16* Kb_ = K + (size_t)(b * T_SEQ) * CDIM + h * DH;
    const __bf16* Vb_ = Vt + (size_t)(b * NH + h) * DH * T_SEQ;
    __bf16* Pw = &ldsP[w][0];

// stage one 64x64 K-tile and V-tile (8KB each) at kv0 into dstK/dstV.
// chunk c in [0,512): row=c>>3, slot j=c&7 holds global chunk j^(row&7).
// global_load_lds dest = wave-uniform base + lane*16 (linear).
#define STAGE_KV(dstK, dstV, kv0) do {                                        \
    _Pragma("unroll")                                                          \
    for (int p = 0; p < 2; ++p) {                                              \
        const int c  = p * 256 + w * 64 + lane;                                \
        const int rr = c >> 3, jj = c & 7;                                     \
        const int sj = (jj ^ (rr & 7)) << 3;                                   \
        GLD_TO_LDS16(Kb_ + (size_t)((kv0) + rr) * CDIM + sj,                   \
                     (dstK) + (size_t)(p * 256 + w * 64) * 8);                 \
        GLD_TO_LDS16(Vb_ + (size_t)rr * T_SEQ + (kv0) + sj,                    \
                     (dstV) + (size_t)(p * 256 + w * 64) * 8);                 \
    } } while (0)

    for (int selq = 0; selq < 2; ++selq) {
        const int qt = selq ? (31 - pj) : pj;
        const int q0 = qt * 64 + w * 16;

        const __bf16* Qrow = Q + (size_t)(b * T_SEQ + q0 + l15) * CDIM + h * DH;
        const bf16x8 qf0 = *reinterpret_cast<const bf16x8*>(Qrow + g * 8);
        const bf16x8 qf1 = *reinterpret_cast<const bf16x8*>(Qrow + 32 + g * 8);

        f32x4 o[4];
#pragma unroll
        for (int nf = 0; nf < 4; ++nf) o[nf] = (f32x4){0.f, 0.f, 0.f, 0.f};
        float m_run = -1e30f, l_run = 0.f;

        int cur = 0;
        STAGE_KV(&ldsK[0][0], &ldsV[0][0], 0);
        __syncthreads();

        for (int t = 0; t <= qt; ++t) {
            const int kv0 = t * 64;
            if (t < qt) {   // prefetch next tile into other buffer (hides under compute)
                if (cur == 0) STAGE_KV(&ldsK[1][0], &ldsV[1][0], kv0 + 64);
                else          STAGE_KV(&ldsK[0][0], &ldsV[0][0], kv0 + 64);
            }
            const __bf16* kb_lds = &ldsK[cur][0];
            const __bf16* vb_lds = &ldsV[cur][0];

            // S^T tile: lane holds col q = q0+l15, rows k = kv0 + kbt*16 + g*4 + ii
            f32x4 s[4];
            __builtin_amdgcn_s_setprio(1);
#pragma unroll
            for (int kbt = 0; kbt < 4; ++kbt) {
                const int R = kbt * 16 + l15;
                const bf16x8 kf0 = *reinterpret_cast<const bf16x8*>(
                    kb_lds + R * 64 + ((g ^ (R & 7)) << 3));
                const bf16x8 kf1 = *reinterpret_cast<const bf16x8*>(
                    kb_lds + R * 64 + (((4 + g) ^ (R & 7)) << 3));
                f32x4 z = (f32x4){0.f, 0.f, 0.f, 0.f};
                z = mfma16(kf0, qf0, z);
                z = mfma16(kf1, qf1, z);
                s[kbt] = z;
            }
            __builtin_amdgcn_s_setprio(0);
            if (t == qt) {   // diagonal tile: causal mask
#pragma unroll
                for (int kbt = 0; kbt < 4; ++kbt)
#pragma unroll
                    for (int ii = 0; ii < 4; ++ii)
                        if (kv0 + kbt * 16 + g * 4 + ii > q0 + l15) s[kbt][ii] = -1e30f;
            }
            float tm = -1e30f;
#pragma unroll
            for (int kbt = 0; kbt < 4; ++kbt)
#pragma unroll
                for (int ii = 0; ii < 4; ++ii) tm = fmaxf(tm, s[kbt][ii]);
            tm = fmaxf(tm, __shfl_xor(tm, 16));
            tm = fmaxf(tm, __shfl_xor(tm, 32));
            // T13 defer-max: only rescale when some row's max grew by > 8.
            if (!__all(tm - m_run <= 8.f)) {
                const float mnew = fmaxf(m_run, tm);
                const float alpha = __expf(m_run - mnew);
                l_run *= alpha;
#pragma unroll
                for (int ii = 0; ii < 4; ++ii) {
                    const float ai = __shfl(alpha, g * 4 + ii);
#pragma unroll
                    for (int nf = 0; nf < 4; ++nf) o[nf][ii] *= ai;
                }
                m_run = mnew;
            }
            float ts = 0.f;
#pragma unroll
            for (int kbt = 0; kbt < 4; ++kbt)
#pragma unroll
                for (int ii = 0; ii < 4; ++ii) {
                    const float p = __expf(s[kbt][ii] - m_run);
                    s[kbt][ii] = p;
                    ts += p;
                }
            ts += __shfl_xor(ts, 16);
            ts += __shfl_xor(ts, 32);
            l_run += ts;
            // P -> LDS [q=l15][k], 8B packed writes
#pragma unroll
            for (int kbt = 0; kbt < 4; ++kbt) {
                bf16x4v pk = { (__bf16)s[kbt][0], (__bf16)s[kbt][1],
                               (__bf16)s[kbt][2], (__bf16)s[kbt][3] };
                *reinterpret_cast<bf16x4v*>(Pw + l15 * 72 + kbt * 16 + g * 4) = pk;
            }
            // PV: A = P[q][k] from LDS, B = V[k][d] from swizzled LDS V-tile
            __builtin_amdgcn_s_setprio(1);
#pragma unroll
            for (int ks = 0; ks < 2; ++ks) {
                const bf16x8 pf = *reinterpret_cast<const bf16x8*>(Pw + l15 * 72 + ks * 32 + g * 8);
#pragma unroll
                for (int nf = 0; nf < 4; ++nf) {
                    const int dd = nf * 16 + l15;
                    const bf16x8 vf = *reinterpret_cast<const bf16x8*>(
                        vb_lds + dd * 64 + ((((ks << 2) + g) ^ (dd & 7)) << 3));
                    o[nf] = mfma16(pf, vf, o[nf]);
                }
            }
            __builtin_amdgcn_s_setprio(0);
            __syncthreads();   // next buffer staged (vmcnt drained) + all waves done with cur
            cur ^= 1;
        }
        // epilogue: divide by l, write [B,T,C] bf16
#pragma unroll
        for (int ii = 0; ii < 4; ++ii) {
            const float li = __shfl(l_run, g * 4 + ii);
            const float inv = 1.f / li;
            __bf16* Yr = Y + (size_t)(b * T_SEQ + q0 + g * 4 + ii) * CDIM + h * DH;
#pragma unroll
            for (int nf = 0; nf < 4; ++nf)
                Yr[nf * 16 + l15] = (__bf16)(o[nf][ii] * inv);
        }
    }
#undef STAGE_KV
}

extern "C" void kernel_launch(void* const* d_in, const int* in_sizes, int n_in,
                              void* d_out, int out_size, void* d_ws, size_t ws_size,
                              hipStream_t stream) {
    const float* x  = (const float*)d_in[0];
    const float* Wq = (const float*)d_in[1];
    const float* bq = (const float*)d_in[2];
    const float* Wk = (const float*)d_in[3];
    const float* bk = (const float*)d_in[4];
    const float* Wv = (const float*)d_in[5];
    const float* bv = (const float*)d_in[6];
    const float* Wp = (const float*)d_in[7];
    const float* bp = (const float*)d_in[8];
    float* out = (float*)d_out;
    (void)in_sizes; (void)n_in; (void)out_size; (void)ws_size;

    char* ws = (char*)d_ws;
    const size_t MT = (size_t)BDIM * T_SEQ;                  // 4096 rows
    const size_t SZ = MT * CDIM * sizeof(__bf16);            // 8 MiB
    __bf16* Xb = (__bf16*)(ws);                              // [4096][1024]
    __bf16* Wt = (__bf16*)(ws + SZ);                         // [4096][1024] (q,k,v,p stacked)
    __bf16* Qb = (__bf16*)(ws + 2 * SZ);                     // [B,T,C] (pre-scaled 1/8)
    __bf16* Kb = (__bf16*)(ws + 3 * SZ);                     // [B,T,C]
    __bf16* Vt = (__bf16*)(ws + 4 * SZ);                     // [B,H,Dh,T]
    __bf16* Ya = Xb;                                         // alias: Xb dead after QKV gemm

    // fused convert+transpose: blocks [0,4096) convert x, [4096,8192) transpose W
    k_prep<<<dim3(8192), 256, 0, stream>>>(x, Xb, Wq, Wk, Wv, Wp, Wt);
    k_gemm<0><<<dim3(3 * CDIM / BN, MT / BM), 256, 0, stream>>>(
        Xb, Wt, bq, bk, bv, Qb, Kb, Vt, nullptr);
    k_attn<<<dim3(512), 256, 0, stream>>>(Qb, Kb, Vt, Ya);
    k_gemm<1><<<dim3(CDIM / BN, MT / BM), 256, 0, stream>>>(
        Ya, Wt + (size_t)3 * CDIM * CDIM, bp, nullptr, nullptr,
        nullptr, nullptr, nullptr, out);
}